// Round 1
// baseline (233.497 us; speedup 1.0000x reference)
//
#include <hip/hip_runtime.h>
#include <math.h>

#define BDIM 4
#define NDIM 4096
#define MDIM 4096
#define CDIM 128
#define KSEL 32

// ---------------------------------------------------------------------------
// Precompute folded weights into ws:
//   pre[0:3*C]   = Wqa = Wq @ Wa          (3 x C)
//   pre[3C:6C]   = Wka = Wk @ Wa          (3 x C)
//   pre[6C:7C]   = ca  = (bq - bk) @ Wa + ba   (C)
// fp64 accumulation: refactor error ~1e-7 absolute, negligible vs threshold.
// ---------------------------------------------------------------------------
__global__ void precompute_kernel(const float* __restrict__ Wq, const float* __restrict__ bq,
                                  const float* __restrict__ Wk, const float* __restrict__ bk,
                                  const float* __restrict__ Wa, const float* __restrict__ ba,
                                  float* __restrict__ pre) {
    int c = threadIdx.x;  // 0..127
    for (int r = 0; r < 3; ++r) {
        double sq = 0.0, sk = 0.0;
        for (int k = 0; k < CDIM; ++k) {
            double wa = (double)Wa[k * CDIM + c];
            sq += (double)Wq[r * CDIM + k] * wa;
            sk += (double)Wk[r * CDIM + k] * wa;
        }
        pre[r * CDIM + c]       = (float)sq;
        pre[(3 + r) * CDIM + c] = (float)sk;
    }
    double sc = (double)ba[c];
    for (int k = 0; k < CDIM; ++k)
        sc += ((double)bq[k] - (double)bk[k]) * (double)Wa[k * CDIM + c];
    pre[6 * CDIM + c] = (float)sc;
}

// ---------------------------------------------------------------------------
// Main kernel: 1 wave per anchor, 4 anchors (4 waves) per 256-thread block.
// All blocks of one batch stage that batch's 4096 neighbor xyz into LDS (SoA).
// Phase 1: ball query (ordered compaction via ballot).
// Phase 2: per selected neighbor, channel-softmax + max-accumulate.
// Lane handles channels c0=2*lane, c0+1 (float2 I/O everywhere).
// ---------------------------------------------------------------------------
__launch_bounds__(256)
__global__ void attn_kernel(const float* __restrict__ anchor,
                            const float* __restrict__ neighbor,
                            const float* __restrict__ Wd,
                            const float* __restrict__ bd,
                            const float* __restrict__ pre,
                            float* __restrict__ out) {
    __shared__ float xs[MDIM], ys[MDIM], zs[MDIM];
    __shared__ int   lists[4][KSEL];

    const int b    = blockIdx.x >> 10;          // 1024 blocks per batch
    const int n0   = (blockIdx.x & 1023) << 2;  // 4 anchors per block
    const int tid  = threadIdx.x;
    const int w    = tid >> 6;
    const int lane = tid & 63;

    // --- stage neighbors for this batch into LDS (SoA), fully coalesced ---
    const float* nb = neighbor + (size_t)b * MDIM * 3;
    for (int i = tid; i < 3 * MDIM; i += 256) {
        float v = nb[i];
        int m = i / 3;
        int r = i - 3 * m;
        if (r == 0) xs[m] = v;
        else if (r == 1) ys[m] = v;
        else zs[m] = v;
    }
    __syncthreads();

    const int n = n0 + w;
    const float* ap = anchor + ((size_t)b * NDIM + n) * 3;
    const float ax = ap[0], ay = ap[1], az = ap[2];

    // --- per-lane channel weights (2 channels per lane) ---
    const float2* pre2 = (const float2*)pre;
    const float2* wdp  = (const float2*)Wd;
    const float2* bdp  = (const float2*)bd;
    const float2 wqa0 = pre2[0 * 64 + lane], wqa1 = pre2[1 * 64 + lane], wqa2 = pre2[2 * 64 + lane];
    const float2 wka0 = pre2[3 * 64 + lane], wka1 = pre2[4 * 64 + lane], wka2 = pre2[5 * 64 + lane];
    const float2 cav  = pre2[6 * 64 + lane];
    const float2 wd0 = wdp[0 * 64 + lane], wd1 = wdp[1 * 64 + lane], wd2 = wdp[2 * 64 + lane];
    const float2 bdv = bdp[lane];

    const float qa0 = ax * wqa0.x + ay * wqa1.x + az * wqa2.x + cav.x;
    const float qa1 = ax * wqa0.y + ay * wqa1.y + az * wqa2.y + cav.y;
    const float ad0 = ax * wd0.x + ay * wd1.x + az * wd2.x + bdv.x;
    const float ad1 = ax * wd0.y + ay * wd1.y + az * wd2.y + bdv.y;

    // --- phase 1: ball query (first KSEL in index order with d2 < R2) ---
    constexpr float R2 = (float)(0.12 * 0.12);
    int cnt = 0;
    for (int base = 0; base < MDIM && cnt < KSEL; base += 64) {
        int m = base + lane;
        // match no-fma fp32 evaluation: ((dx*dx + dy*dy) + dz*dz)
        float dx = __fsub_rn(ax, xs[m]);
        float dy = __fsub_rn(ay, ys[m]);
        float dz = __fsub_rn(az, zs[m]);
        float d2 = __fadd_rn(__fadd_rn(__fmul_rn(dx, dx), __fmul_rn(dy, dy)), __fmul_rn(dz, dz));
        bool in = d2 < R2;
        unsigned long long mk = __ballot(in);
        int before = __popcll(mk & ((1ull << lane) - 1ull));
        int pos = cnt + before;
        if (in && pos < KSEL) lists[w][pos] = m;
        cnt += __popcll(mk);
    }
    int eff = cnt < KSEL ? cnt : KSEL;
    if (cnt == 0) {  // pad semantics: no hits -> slot 0 holds index 0
        if (lane == 0) lists[w][0] = 0;
        eff = 1;
    }
    __syncthreads();  // make per-wave LDS list writes safely visible

    // --- phase 2: channel softmax + max-accumulate over selected neighbors ---
    float acc0 = -1e30f, acc1 = -1e30f;
    for (int j = 0; j < eff; ++j) {
        int m = lists[w][j];
        float nx = xs[m], ny = ys[m], nz = zs[m];  // broadcast reads
        float l0 = qa0 - (nx * wka0.x + ny * wka1.x + nz * wka2.x);
        float l1 = qa1 - (nx * wka0.y + ny * wka1.y + nz * wka2.y);
        // |logits| bounded (<~5 typical, <60 worst case): exp safe without max-sub
        float e0 = __expf(l0);
        float e1 = __expf(l1);
        float s = e0 + e1;
        s += __shfl_xor(s, 32);
        s += __shfl_xor(s, 16);
        s += __shfl_xor(s, 8);
        s += __shfl_xor(s, 4);
        s += __shfl_xor(s, 2);
        s += __shfl_xor(s, 1);
        float inv = 1.0f / s;
        float d0 = ad0 - (nx * wd0.x + ny * wd1.x + nz * wd2.x);
        float d1 = ad1 - (nx * wd0.y + ny * wd1.y + nz * wd2.y);
        acc0 = fmaxf(acc0, d0 * (e0 * inv));
        acc1 = fmaxf(acc1, d1 * (e1 * inv));
    }

    float2 o;
    o.x = acc0;
    o.y = acc1;
    ((float2*)out)[((size_t)b * NDIM + n) * 64 + lane] = o;
}

extern "C" void kernel_launch(void* const* d_in, const int* in_sizes, int n_in,
                              void* d_out, int out_size, void* d_ws, size_t ws_size,
                              hipStream_t stream) {
    const float* anchor   = (const float*)d_in[0];
    const float* neighbor = (const float*)d_in[1];
    const float* Wq = (const float*)d_in[2];
    const float* bq = (const float*)d_in[3];
    const float* Wk = (const float*)d_in[4];
    const float* bk = (const float*)d_in[5];
    const float* Wd = (const float*)d_in[6];
    const float* bd = (const float*)d_in[7];
    const float* Wa = (const float*)d_in[8];
    const float* ba = (const float*)d_in[9];
    float* out = (float*)d_out;
    float* pre = (float*)d_ws;  // 7*C floats = 3584 B

    precompute_kernel<<<dim3(1), dim3(CDIM), 0, stream>>>(Wq, bq, Wk, bk, Wa, ba, pre);
    attn_kernel<<<dim3((BDIM * NDIM) / 4), dim3(256), 0, stream>>>(anchor, neighbor, Wd, bd, pre, out);
}

// Round 2
// 138.289 us; speedup vs baseline: 1.6885x; 1.6885x over previous
//
#include <hip/hip_runtime.h>
#include <math.h>

#define BDIM 4
#define NDIM 4096
#define MDIM 4096
#define CDIM 128
#define KSEL 32

// ws layout (floats): [0, 7C) folded weights; then xs[B*M], ys[B*M], zs[B*M]
//   pre[0:3C)  = Wqa = Wq @ Wa
//   pre[3C:6C) = Wka = Wk @ Wa
//   pre[6C:7C) = ca  = (bq - bk) @ Wa + ba
#define PRE_FLOATS (7 * CDIM)
#define SOA_FLOATS (3 * BDIM * MDIM)

// ---------------------------------------------------------------------------
// Folded-weight precompute: 7 blocks x 128 threads, fp64 accumulation
// (refactor error ~1e-7 absolute — negligible vs 1.98e-4 threshold).
// ---------------------------------------------------------------------------
__global__ void precompute_kernel(const float* __restrict__ Wq, const float* __restrict__ bq,
                                  const float* __restrict__ Wk, const float* __restrict__ bk,
                                  const float* __restrict__ Wa, const float* __restrict__ ba,
                                  float* __restrict__ pre) {
    const int c = threadIdx.x;   // 0..127
    const int r = blockIdx.x;    // 0..6
    if (r < 3) {
        double s0 = 0, s1 = 0, s2 = 0, s3 = 0;
        for (int k = 0; k < CDIM; k += 4) {
            s0 += (double)Wq[r * CDIM + k + 0] * (double)Wa[(k + 0) * CDIM + c];
            s1 += (double)Wq[r * CDIM + k + 1] * (double)Wa[(k + 1) * CDIM + c];
            s2 += (double)Wq[r * CDIM + k + 2] * (double)Wa[(k + 2) * CDIM + c];
            s3 += (double)Wq[r * CDIM + k + 3] * (double)Wa[(k + 3) * CDIM + c];
        }
        pre[r * CDIM + c] = (float)((s0 + s1) + (s2 + s3));
    } else if (r < 6) {
        const int rr = r - 3;
        double s0 = 0, s1 = 0, s2 = 0, s3 = 0;
        for (int k = 0; k < CDIM; k += 4) {
            s0 += (double)Wk[rr * CDIM + k + 0] * (double)Wa[(k + 0) * CDIM + c];
            s1 += (double)Wk[rr * CDIM + k + 1] * (double)Wa[(k + 1) * CDIM + c];
            s2 += (double)Wk[rr * CDIM + k + 2] * (double)Wa[(k + 2) * CDIM + c];
            s3 += (double)Wk[rr * CDIM + k + 3] * (double)Wa[(k + 3) * CDIM + c];
        }
        pre[r * CDIM + c] = (float)((s0 + s1) + (s2 + s3));
    } else {
        double sc = (double)ba[c];
        for (int k = 0; k < CDIM; ++k)
            sc += ((double)bq[k] - (double)bk[k]) * (double)Wa[k * CDIM + c];
        pre[6 * CDIM + c] = (float)sc;
    }
}

// ---------------------------------------------------------------------------
// Interleaved (B,M,3) -> SoA xs/ys/zs in ws. Tiny, fully parallel.
// ---------------------------------------------------------------------------
__global__ void transpose_kernel(const float* __restrict__ nb, float* __restrict__ xs,
                                 float* __restrict__ ys, float* __restrict__ zs) {
    int i = blockIdx.x * 256 + threadIdx.x;
    if (i < BDIM * MDIM) {
        float x = nb[3 * i + 0];
        float y = nb[3 * i + 1];
        float z = nb[3 * i + 2];
        xs[i] = x; ys[i] = y; zs[i] = z;
    }
}

// ---------------------------------------------------------------------------
// Main kernel: 1 wave per anchor, 4 waves / 256-thread block, no block-wide
// barriers. Neighbors read from L1/L2 (48 KB/batch, cache-resident).
// Phase 1: strip-mined ballot scan (8 steps/strip, early exit per strip).
// Phase 2: one parallel xyz gather into LDS, then 4-way-unrolled
// channel-softmax + max-accumulate (interleaved shuffle chains).
// ---------------------------------------------------------------------------
__launch_bounds__(256)
__global__ void attn_kernel(const float* __restrict__ anchor,
                            const float* __restrict__ neighbor,  // interleaved fallback
                            const float* __restrict__ Wd,
                            const float* __restrict__ bd,
                            const float* __restrict__ pre,
                            const float* __restrict__ xs,
                            const float* __restrict__ ys,
                            const float* __restrict__ zs,
                            const int soa,
                            float* __restrict__ out) {
    __shared__ int    lists[4][KSEL];
    __shared__ float4 nxyz[4][KSEL];

    const int b    = blockIdx.x >> 10;          // 1024 blocks per batch
    const int n0   = (blockIdx.x & 1023) << 2;  // 4 anchors per block
    const int tid  = threadIdx.x;
    const int w    = tid >> 6;
    const int lane = tid & 63;

    const int n = n0 + w;
    const float* ap = anchor + ((size_t)b * NDIM + n) * 3;
    const float ax = ap[0], ay = ap[1], az = ap[2];

    const float* xb = xs + (size_t)b * MDIM;
    const float* yb = ys + (size_t)b * MDIM;
    const float* zb = zs + (size_t)b * MDIM;
    const float* nbb = neighbor + (size_t)b * MDIM * 3;

    // --- per-lane channel weights (2 channels per lane) ---
    const float2* pre2 = (const float2*)pre;
    const float2* wdp  = (const float2*)Wd;
    const float2* bdp  = (const float2*)bd;
    const float2 wqa0 = pre2[0 * 64 + lane], wqa1 = pre2[1 * 64 + lane], wqa2 = pre2[2 * 64 + lane];
    const float2 wka0 = pre2[3 * 64 + lane], wka1 = pre2[4 * 64 + lane], wka2 = pre2[5 * 64 + lane];
    const float2 cav  = pre2[6 * 64 + lane];
    const float2 wd0 = wdp[0 * 64 + lane], wd1 = wdp[1 * 64 + lane], wd2 = wdp[2 * 64 + lane];
    const float2 bdv = bdp[lane];

    const float qa0 = ax * wqa0.x + ay * wqa1.x + az * wqa2.x + cav.x;
    const float qa1 = ax * wqa0.y + ay * wqa1.y + az * wqa2.y + cav.y;
    const float ad0 = ax * wd0.x + ay * wd1.x + az * wd2.x + bdv.x;
    const float ad1 = ax * wd0.y + ay * wd1.y + az * wd2.y + bdv.y;

    // --- phase 1: ball query, strip-mined (8 steps of 64 per strip) ---
    constexpr float R2 = (float)(0.12 * 0.12);
    const unsigned long long lanelt = (1ull << lane) - 1ull;
    int cnt = 0;
    for (int s = 0; s < MDIM / 512 && cnt < KSEL; ++s) {
        const int base = s * 512;
        float d2v[8];
        #pragma unroll
        for (int t = 0; t < 8; ++t) {
            const int m = base + (t << 6) + lane;
            float nx, ny, nz;
            if (soa) { nx = xb[m]; ny = yb[m]; nz = zb[m]; }
            else     { const float* p = nbb + 3 * m; nx = p[0]; ny = p[1]; nz = p[2]; }
            // no-fma fp32 evaluation: ((dx*dx + dy*dy) + dz*dz), matches np ref
            float dx = __fsub_rn(ax, nx);
            float dy = __fsub_rn(ay, ny);
            float dz = __fsub_rn(az, nz);
            d2v[t] = __fadd_rn(__fadd_rn(__fmul_rn(dx, dx), __fmul_rn(dy, dy)), __fmul_rn(dz, dz));
        }
        #pragma unroll
        for (int t = 0; t < 8; ++t) {
            const bool in = d2v[t] < R2;
            const unsigned long long mk = __ballot(in);
            const int pos = cnt + __popcll(mk & lanelt);
            if (in && pos < KSEL) lists[w][pos] = base + (t << 6) + lane;
            cnt += __popcll(mk);
        }
    }
    int eff = cnt < KSEL ? cnt : KSEL;
    if (cnt == 0) {  // pad semantics: no hits -> slot 0 holds index 0
        if (lane == 0) lists[w][0] = 0;
        eff = 1;
    }
    const int eff4 = (eff + 3) & ~3;  // pad with first index: idempotent under max
    if (lane == 0) {
        for (int j = eff; j < eff4; ++j) lists[w][j] = lists[w][0];
    }
    __builtin_amdgcn_wave_barrier();

    // --- gather selected xyz into LDS in one parallel round ---
    if (lane < eff4) {
        const int m = lists[w][lane];
        float nx, ny, nz;
        if (soa) { nx = xb[m]; ny = yb[m]; nz = zb[m]; }
        else     { const float* p = nbb + 3 * m; nx = p[0]; ny = p[1]; nz = p[2]; }
        nxyz[w][lane] = make_float4(nx, ny, nz, 0.f);
    }
    __builtin_amdgcn_wave_barrier();

    // --- phase 2: channel softmax + max-accumulate, 4-way unrolled ---
    float acc0 = -1e30f, acc1 = -1e30f;
    for (int j = 0; j < eff4; j += 4) {
        float e0v[4], e1v[4], sv[4], p0[4], p1[4];
        #pragma unroll
        for (int t = 0; t < 4; ++t) {
            const float4 v = nxyz[w][j + t];
            const float l0 = qa0 - (v.x * wka0.x + v.y * wka1.x + v.z * wka2.x);
            const float l1 = qa1 - (v.x * wka0.y + v.y * wka1.y + v.z * wka2.y);
            e0v[t] = __expf(l0);
            e1v[t] = __expf(l1);
            sv[t] = e0v[t] + e1v[t];
            const float d0 = ad0 - (v.x * wd0.x + v.y * wd1.x + v.z * wd2.x);
            const float d1 = ad1 - (v.x * wd0.y + v.y * wd1.y + v.z * wd2.y);
            p0[t] = d0 * e0v[t];
            p1[t] = d1 * e1v[t];
        }
        #pragma unroll
        for (int off = 32; off >= 1; off >>= 1) {
            #pragma unroll
            for (int t = 0; t < 4; ++t) sv[t] += __shfl_xor(sv[t], off);
        }
        #pragma unroll
        for (int t = 0; t < 4; ++t) {
            const float inv = __builtin_amdgcn_rcpf(sv[t]);
            acc0 = fmaxf(acc0, p0[t] * inv);
            acc1 = fmaxf(acc1, p1[t] * inv);
        }
    }

    float2 o;
    o.x = acc0;
    o.y = acc1;
    ((float2*)out)[((size_t)b * NDIM + n) * 64 + lane] = o;
}

extern "C" void kernel_launch(void* const* d_in, const int* in_sizes, int n_in,
                              void* d_out, int out_size, void* d_ws, size_t ws_size,
                              hipStream_t stream) {
    const float* anchor   = (const float*)d_in[0];
    const float* neighbor = (const float*)d_in[1];
    const float* Wq = (const float*)d_in[2];
    const float* bq = (const float*)d_in[3];
    const float* Wk = (const float*)d_in[4];
    const float* bk = (const float*)d_in[5];
    const float* Wd = (const float*)d_in[6];
    const float* bd = (const float*)d_in[7];
    const float* Wa = (const float*)d_in[8];
    const float* ba = (const float*)d_in[9];
    float* out = (float*)d_out;
    float* pre = (float*)d_ws;

    const int soa = ws_size >= (size_t)(PRE_FLOATS + SOA_FLOATS) * sizeof(float);
    float* xs = pre + PRE_FLOATS;
    float* ys = xs + BDIM * MDIM;
    float* zs = ys + BDIM * MDIM;

    precompute_kernel<<<dim3(7), dim3(CDIM), 0, stream>>>(Wq, bq, Wk, bk, Wa, ba, pre);
    if (soa) {
        transpose_kernel<<<dim3((BDIM * MDIM + 255) / 256), dim3(256), 0, stream>>>(neighbor, xs, ys, zs);
    }
    attn_kernel<<<dim3((BDIM * NDIM) / 4), dim3(256), 0, stream>>>(
        anchor, neighbor, Wd, bd, pre, xs, ys, zs, soa, out);
}